// Round 8
// baseline (390.245 us; speedup 1.0000x reference)
//
#include <hip/hip_runtime.h>

typedef unsigned short u16;
typedef __attribute__((ext_vector_type(8))) short s16x8;      // raw 16B staging
typedef __attribute__((ext_vector_type(8))) _Float16 f16x8;   // MFMA fragments
typedef __attribute__((ext_vector_type(4))) float f32x4;

#define ASYNC16(gp, lp) \
  __builtin_amdgcn_global_load_lds((__attribute__((address_space(1))) void*)(gp), \
                                   (__attribute__((address_space(3))) void*)(lp), 16, 0, 0)

__device__ __forceinline__ u16 f2h(float f) {
  _Float16 h = (_Float16)f;
  union { _Float16 h; u16 u; } v; v.h = h;
  return v.u;
}

__device__ __forceinline__ int swz4(int row) { return (row & 3) ^ ((row >> 2) & 3); }

// ---------------------------------------------------------------------------
// prep: cast trg/src fp32->fp16; transpose+cast weights into Wt[n][k] fp16.
// (verified round 4)
// ---------------------------------------------------------------------------
__global__ __launch_bounds__(256) void prep_kernel(
    const float* __restrict__ trg, const float* __restrict__ src,
    const float* __restrict__ Wsa, const float* __restrict__ Wea,
    u16* __restrict__ trg_h, u16* __restrict__ src_h, u16* __restrict__ wt)
{
  int blk = blockIdx.x, tid = threadIdx.x;
  if (blk < 8192) {
    const float* sp = (blk < 4096) ? trg : src;
    u16* dp = (blk < 4096) ? trg_h : src_h;
    size_t base = ((size_t)(blk & 4095) * 256 + tid) * 8;
    float4 a = *(const float4*)(sp + base);
    float4 c = *(const float4*)(sp + base + 4);
    s16x8 o;
    o[0] = (short)f2h(a.x); o[1] = (short)f2h(a.y);
    o[2] = (short)f2h(a.z); o[3] = (short)f2h(a.w);
    o[4] = (short)f2h(c.x); o[5] = (short)f2h(c.y);
    o[6] = (short)f2h(c.z); o[7] = (short)f2h(c.w);
    *(s16x8*)(dp + base) = o;
  } else {
    int t = (blk - 8192) * 256 + tid;       // < 524288
    int row = t >> 8, k = t & 255;
    const float* W; int sel, col;
    if (row < 768)       { W = Wsa; sel = row >> 8;              col = row & 255; }
    else if (row < 1024) { W = Wsa; sel = 3;                     col = row & 255; }
    else if (row < 1280) { W = Wea; sel = 0;                     col = row & 255; }
    else if (row < 1792) { W = Wea; sel = ((row - 1280) >> 8) + 1; col = (row - 1280) & 255; }
    else                 { W = Wea; sel = 3;                     col = row & 255; }
    wt[(size_t)row * 256 + k] = f2h(W[sel * 65536 + k * 256 + col]);
  }
}

// ---------------------------------------------------------------------------
// fp16 MFMA GEMM (verified round 4): C[M][N] = A[M][256] @ Bt[N][256]^T + bias.
// ---------------------------------------------------------------------------
__global__ __launch_bounds__(256, 3) void gemm_bias_f16(
    const u16* __restrict__ A, const u16* __restrict__ Bt,
    const float* __restrict__ bias, u16* __restrict__ C, int N)
{
  __shared__ u16 Asm[128 * 32];
  __shared__ u16 Bsm[128 * 32];
  const int tid = threadIdx.x;
  const int wv = tid >> 6, ln = tid & 63;
  const int quad = ln >> 4, l16 = ln & 15;
  const int nblk = blockIdx.x;
  const size_t arow0 = (size_t)blockIdx.y * 128;
  const size_t brow0 = (size_t)nblk * 128;
  const int wr = wv >> 1, wc = wv & 1;
  f32x4 acc[4][4];
  const f32x4 VZERO = {0.f, 0.f, 0.f, 0.f};
#pragma unroll
  for (int i = 0; i < 4; ++i)
#pragma unroll
    for (int j = 0; j < 4; ++j) acc[i][j] = VZERO;

  for (int k0 = 0; k0 < 256; k0 += 32) {
    __syncthreads();
#pragma unroll
    for (int j = 0; j < 2; ++j) {
      int c = (j * 4 + wv) * 64 + ln;
      int row = c >> 2, slot = c & 3;
      int kc = slot ^ swz4(row);
      ASYNC16(A + (arow0 + row) * 256 + k0 + kc * 8, Asm + c * 8);
      ASYNC16(Bt + (brow0 + row) * 256 + k0 + kc * 8, Bsm + c * 8);
    }
    __syncthreads();
    f16x8 af[4], bfr[4];
#pragma unroll
    for (int mt = 0; mt < 4; ++mt) {
      int tr = wr * 64 + mt * 16 + l16;
      int slot = quad ^ swz4(tr);
      af[mt] = *(const f16x8*)(Asm + (tr * 4 + slot) * 8);
    }
#pragma unroll
    for (int nt = 0; nt < 4; ++nt) {
      int tr = wc * 64 + nt * 16 + l16;
      int slot = quad ^ swz4(tr);
      bfr[nt] = *(const f16x8*)(Bsm + (tr * 4 + slot) * 8);
    }
#pragma unroll
    for (int mt = 0; mt < 4; ++mt)
#pragma unroll
      for (int nt = 0; nt < 4; ++nt)
        acc[mt][nt] = __builtin_amdgcn_mfma_f32_16x16x32_f16(af[mt], bfr[nt], acc[mt][nt], 0, 0, 0);
  }
#pragma unroll
  for (int nt = 0; nt < 4; ++nt) {
    int col = nblk * 128 + wc * 64 + nt * 16 + l16;
    float bz = bias[col];
#pragma unroll
    for (int mt = 0; mt < 4; ++mt) {
      size_t row0 = arow0 + wr * 64 + mt * 16 + quad * 4;
#pragma unroll
      for (int r = 0; r < 4; ++r)
        C[(row0 + r) * (size_t)N + col] = f2h(acc[mt][nt][r] + bz);
    }
  }
}

// ---------------------------------------------------------------------------
// MFMA attention, no-max softmax (verified r5-7). Round 8: bank-conflict fix.
//  - Vt stride 264 -> 296 u16 (148 words = 20 mod 32: same 2-way-free class
//    as Ks stride-40 reads; was 132 = 4 mod 32 -> 8-way on vf reads)
//  - V staging remap: row = tid, part = iter -> per-instr writes span 64
//    contiguous u16 = 32 words, 2 lanes/word -> 2-way free (was 4-way).
// ---------------------------------------------------------------------------
__global__ __launch_bounds__(256, 3) void attn_mfma(
    const u16* __restrict__ Qp, int ldq,
    const u16* __restrict__ Kp, int ldk,
    const u16* __restrict__ Vp, int ldv,
    u16* __restrict__ Op)
{
  __shared__ u16 Ks[256 * 40];
  __shared__ u16 Vt[32 * 296];
  __shared__ __align__(16) unsigned Pw[4][32 * 20];
  const int tid = threadIdx.x;
  const int wv = tid >> 6, ln = tid & 63;
  const int quad = ln >> 4, l16 = ln & 15;
  const int lin = blockIdx.x;
  const int qb = (lin >> 3) & 3;
  const int g = ((lin >> 5) << 3) | (lin & 7);   // 0..511, partners share XCD
  const int h = g & 7;
  const size_t rb = (size_t)(g >> 3) * 512;
  const f32x4 VZERO = {0.f, 0.f, 0.f, 0.f};

  f16x8 qf[2];
  const _Float16 qs = (_Float16)0.25503492f;    // (1/sqrt(32)) * log2(e)
#pragma unroll
  for (int mq = 0; mq < 2; ++mq) {
    int qrow = qb * 128 + wv * 32 + mq * 16 + l16;
    qf[mq] = *(const f16x8*)(Qp + (rb + qrow) * (size_t)ldq + h * 32 + quad * 8);
#pragma unroll
    for (int j = 0; j < 8; ++j) qf[mq][j] *= qs;
  }
  f16x8 onesf;
#pragma unroll
  for (int j = 0; j < 8; ++j) onesf[j] = (_Float16)1.0f;

  f32x4 o[2][2], osum[2];
#pragma unroll
  for (int mq = 0; mq < 2; ++mq) { o[mq][0] = VZERO; o[mq][1] = VZERO; osum[mq] = VZERO; }

  for (int kb = 0; kb < 2; ++kb) {
    __syncthreads();
#pragma unroll
    for (int it = 0; it < 4; ++it) {
      // K staging: row = c>>2, part = c&3 (2-way free)
      {
        int c = it * 256 + tid;
        int row = c >> 2, part = c & 3;
        s16x8 kv = *(const s16x8*)(Kp + (rb + kb * 256 + row) * (size_t)ldk + h * 32 + part * 8);
        *(s16x8*)(Ks + row * 40 + part * 8) = kv;
      }
      // V staging: row = tid, part = it (2-way free scalar writes)
      {
        int row = tid, part = it;
        s16x8 vv = *(const s16x8*)(Vp + (rb + kb * 256 + row) * (size_t)ldv + h * 32 + part * 8);
        int kts = row >> 5, l = row & 31;
        int p = 2 * (l & 15) + (l >> 4);           // key permutation
#pragma unroll
        for (int j = 0; j < 8; ++j) Vt[(part * 8 + j) * 296 + kts * 32 + p] = (u16)vv[j];
      }
    }
    __syncthreads();
    for (int kt = 0; kt < 8; ++kt) {
      f16x8 kf0 = *(const f16x8*)(Ks + (kt * 32 + l16) * 40 + quad * 8);
      f16x8 kf1 = *(const f16x8*)(Ks + (kt * 32 + 16 + l16) * 40 + quad * 8);
      f16x8 vf0 = *(const f16x8*)(Vt + l16 * 296 + kt * 32 + quad * 8);
      f16x8 vf1 = *(const f16x8*)(Vt + (16 + l16) * 296 + kt * 32 + quad * 8);
#pragma unroll
      for (int mq = 0; mq < 2; ++mq) {
        f32x4 s0 = __builtin_amdgcn_mfma_f32_16x16x32_f16(qf[mq], kf0, VZERO, 0, 0, 0);
        f32x4 s1 = __builtin_amdgcn_mfma_f32_16x16x32_f16(qf[mq], kf1, VZERO, 0, 0, 0);
#pragma unroll
        for (int r = 0; r < 4; ++r) {
          float e0 = __builtin_amdgcn_exp2f(s0[r]);
          float e1 = __builtin_amdgcn_exp2f(s1[r]);
          union { _Float16 h2[2]; unsigned u; } pk;
          pk.h2[0] = (_Float16)e0; pk.h2[1] = (_Float16)e1;
          Pw[wv][(mq * 16 + quad * 4 + r) * 20 + l16] = pk.u;
        }
      }
#pragma unroll
      for (int mq = 0; mq < 2; ++mq) {
        f16x8 pf = *(const f16x8*)(&Pw[wv][(mq * 16 + l16) * 20 + quad * 4]);
        o[mq][0] = __builtin_amdgcn_mfma_f32_16x16x32_f16(pf, vf0, o[mq][0], 0, 0, 0);
        o[mq][1] = __builtin_amdgcn_mfma_f32_16x16x32_f16(pf, vf1, o[mq][1], 0, 0, 0);
        osum[mq] = __builtin_amdgcn_mfma_f32_16x16x32_f16(pf, onesf, osum[mq], 0, 0, 0);
      }
    }
  }
#pragma unroll
  for (int mq = 0; mq < 2; ++mq)
#pragma unroll
    for (int r = 0; r < 4; ++r) {
      float inv = 1.f / osum[mq][r];
      size_t row = rb + qb * 128 + wv * 32 + mq * 16 + quad * 4 + r;
      Op[row * 256 + h * 32 + l16]      = f2h(o[mq][0][r] * inv);
      Op[row * 256 + h * 32 + 16 + l16] = f2h(o[mq][1][r] * inv);
    }
}

// ---------------------------------------------------------------------------
// O-projection (MFMA) + bias + residual + LayerNorm (verified round 4).
// ---------------------------------------------------------------------------
__global__ __launch_bounds__(256, 3) void lnproj_kernel(
    const u16* __restrict__ A, const u16* __restrict__ Wt,
    const float* __restrict__ bo, const float* resid,
    const float* __restrict__ g, const float* __restrict__ lb,
    float* Hout, u16* __restrict__ Hh, float* __restrict__ norms)
{
  __shared__ u16 Asm[64 * 32];
  __shared__ u16 Bsm[256 * 32];
  const int tid = threadIdx.x;
  const int wv = tid >> 6, ln = tid & 63;
  const int quad = ln >> 4, l16 = ln & 15;
  const size_t arow0 = (size_t)blockIdx.x * 64;
  f32x4 acc[16];
  const f32x4 VZERO = {0.f, 0.f, 0.f, 0.f};
#pragma unroll
  for (int nt = 0; nt < 16; ++nt) acc[nt] = VZERO;

  for (int k0 = 0; k0 < 256; k0 += 32) {
    __syncthreads();
    {
      int c = tid;
      int row = c >> 2, slot = c & 3;
      int kc = slot ^ swz4(row);
      ASYNC16(A + (arow0 + row) * 256 + k0 + kc * 8, Asm + c * 8);
    }
#pragma unroll
    for (int j = 0; j < 4; ++j) {
      int c = (j * 4 + wv) * 64 + ln;
      int row = c >> 2, slot = c & 3;
      int kc = slot ^ swz4(row);
      ASYNC16(Wt + (size_t)row * 256 + k0 + kc * 8, Bsm + c * 8);
    }
    __syncthreads();
    int tr = wv * 16 + l16;
    int aslot = quad ^ swz4(tr);
    f16x8 af = *(const f16x8*)(Asm + (tr * 4 + aslot) * 8);
#pragma unroll
    for (int nt = 0; nt < 16; ++nt) {
      int br = nt * 16 + l16;
      int bslot = quad ^ swz4(br);
      f16x8 bfr = *(const f16x8*)(Bsm + (br * 4 + bslot) * 8);
      acc[nt] = __builtin_amdgcn_mfma_f32_16x16x32_f16(af, bfr, acc[nt], 0, 0, 0);
    }
  }
  float gv[16], bv[16], bov[16];
#pragma unroll
  for (int nt = 0; nt < 16; ++nt) {
    int col = nt * 16 + l16;
    gv[nt] = g[col]; bv[nt] = lb[col]; bov[nt] = bo[col];
  }
#pragma unroll
  for (int r = 0; r < 4; ++r) {
    size_t row = arow0 + wv * 16 + quad * 4 + r;
    const float* rrow = resid + row * 256;
    float vals[16]; float s = 0.f;
#pragma unroll
    for (int nt = 0; nt < 16; ++nt) {
      float v = acc[nt][r] + bov[nt] + rrow[nt * 16 + l16];
      vals[nt] = v; s += v;
    }
#pragma unroll
    for (int m = 1; m < 16; m <<= 1) s += __shfl_xor(s, m);
    float mean = s * (1.f / 256.f);
    float sq = 0.f;
#pragma unroll
    for (int nt = 0; nt < 16; ++nt) { float d = vals[nt] - mean; sq = fmaf(d, d, sq); }
#pragma unroll
    for (int m = 1; m < 16; m <<= 1) sq += __shfl_xor(sq, m);
    float rstd = rsqrtf(sq * (1.f / 256.f) + 1e-5f);
    float ssq = 0.f;
    float* hrow = Hout + row * 256;
#pragma unroll
    for (int nt = 0; nt < 16; ++nt) {
      float hv = (vals[nt] - mean) * rstd * gv[nt] + bv[nt];
      hrow[nt * 16 + l16] = hv;
      if (Hh) Hh[row * 256 + nt * 16 + l16] = f2h(hv);
      ssq = fmaf(hv, hv, ssq);
    }
    if (norms) {
#pragma unroll
      for (int m = 1; m < 16; m <<= 1) ssq += __shfl_xor(ssq, m);
      if (l16 == 0) norms[row] = sqrtf(ssq);
    }
  }
}

// ---------------------------------------------------------------------------
// Fused head (round 8): pooling softmax + weighted pool + fc1 + fc2 + out,
// one block per batch, 512 threads. All intermediates in LDS; weights are
// L2-resident (1.5 MB shared by all 64 blocks).
// ---------------------------------------------------------------------------
__global__ __launch_bounds__(512) void head_kernel(
    const float* __restrict__ norms, const float* __restrict__ h,
    const float* __restrict__ Wfc1, const float* __restrict__ bfc1,
    const float* __restrict__ Wfc2, const float* __restrict__ bfc2,
    const float* __restrict__ Wout, const float* __restrict__ bout,
    float* __restrict__ out)
{
  int b = blockIdx.x, tid = threadIdx.x;
  int ln = tid & 63, wvi = tid >> 6;       // 8 waves
  __shared__ float w[512], red[16], part[512], px[256], x1[512];

  // softmax over 512 atom norms
  float n = norms[b * 512 + tid];
  float mx = n;
#pragma unroll
  for (int m = 1; m < 64; m <<= 1) mx = fmaxf(mx, __shfl_xor(mx, m));
  if (ln == 0) red[wvi] = mx;
  __syncthreads();
  mx = red[0];
#pragma unroll
  for (int i = 1; i < 8; ++i) mx = fmaxf(mx, red[i]);
  float e = __expf(n - mx);
  float s = e;
#pragma unroll
  for (int m = 1; m < 64; m <<= 1) s += __shfl_xor(s, m);
  if (ln == 0) red[8 + wvi] = s;
  __syncthreads();
  s = red[8];
#pragma unroll
  for (int i = 1; i < 8; ++i) s += red[8 + i];
  w[tid] = e / s;
  __syncthreads();

  // pooled[d] = sum_a w[a] * h[b,a,d]; split a-range over thread halves
  {
    int d = tid & 255, half = tid >> 8;          // half in {0,1}
    const float* hb = h + ((size_t)b * 512 + half * 256) * 256 + d;
    const float* wb = w + half * 256;
    float acc = 0.f;
#pragma unroll 8
    for (int a = 0; a < 256; ++a) acc = fmaf(wb[a], hb[(size_t)a * 256], acc);
    part[tid] = acc;
  }
  __syncthreads();
  if (tid < 256) px[tid] = part[tid] + part[tid + 256];
  __syncthreads();

  // fc1 (256 -> 512) + relu
  {
    float a = bfc1[tid];
#pragma unroll 8
    for (int d = 0; d < 256; ++d) a = fmaf(px[d], Wfc1[d * 512 + tid], a);
    x1[tid] = fmaxf(a, 0.f);
  }
  __syncthreads();

  // fc2 (512 -> 512) + relu, then Wout (512 -> 2) reduction
  float a = bfc2[tid];
#pragma unroll 8
  for (int d = 0; d < 512; ++d) a = fmaf(x1[d], Wfc2[d * 512 + tid], a);
  a = fmaxf(a, 0.f);
  float p0 = a * Wout[tid * 2];
  float p1 = a * Wout[tid * 2 + 1];
#pragma unroll
  for (int m = 1; m < 64; m <<= 1) { p0 += __shfl_xor(p0, m); p1 += __shfl_xor(p1, m); }
  if (ln == 0) { red[wvi] = p0; red[8 + wvi] = p1; }
  __syncthreads();
  if (tid == 0) {
    float t = 0.f;
#pragma unroll
    for (int i = 0; i < 8; ++i) t += red[i];
    out[b * 2] = t + bout[0];
  }
  if (tid == 1) {
    float t = 0.f;
#pragma unroll
    for (int i = 0; i < 8; ++i) t += red[8 + i];
    out[b * 2 + 1] = t + bout[1];
  }
}

// ---------------------------------------------------------------------------
extern "C" void kernel_launch(void* const* d_in, const int* in_sizes, int n_in,
                              void* d_out, int out_size, void* d_ws, size_t ws_size,
                              hipStream_t stream) {
  const float* trg  = (const float*)d_in[0];
  const float* src  = (const float*)d_in[1];
  const float* Wsa  = (const float*)d_in[2];
  const float* bsa  = (const float*)d_in[3];
  const float* Wea  = (const float*)d_in[4];
  const float* bea  = (const float*)d_in[5];
  const float* lng  = (const float*)d_in[6];
  const float* lnb  = (const float*)d_in[7];
  const float* Wfc1 = (const float*)d_in[8];
  const float* bfc1 = (const float*)d_in[9];
  const float* Wfc2 = (const float*)d_in[10];
  const float* bfc2 = (const float*)d_in[11];
  const float* Wout = (const float*)d_in[12];
  const float* bout = (const float*)d_in[13];
  float* out = (float*)d_out;

  const size_t M = 32768;  // B*A
  char* ws = (char*)d_ws;
  u16* trg_h = (u16*)ws;                ws += M * 256 * 2;
  u16* src_h = (u16*)ws;                ws += M * 256 * 2;
  u16* wt     = (u16*)ws;               ws += 2048 * 256 * 2;
  u16* qkv    = (u16*)ws;               ws += M * 768 * 2;
  u16* attnb  = (u16*)ws;               ws += M * 256 * 2;
  float* hbuf = (float*)ws;             ws += M * 256 * 4;
  u16* hh     = (u16*)ws;               ws += M * 256 * 2;
  float* norms = (float*)ws;            ws += M * 4;

  u16* wt_sa_qkv = wt;
  u16* wt_sa_o   = wt + 768 * 256;
  u16* wt_ea_q   = wt + 1024 * 256;
  u16* wt_ea_kv  = wt + 1280 * 256;
  u16* wt_ea_o   = wt + 1792 * 256;
  u16* kvb = qkv + M * 256;

  prep_kernel<<<10240, 256, 0, stream>>>(trg, src, Wsa, Wea, trg_h, src_h, wt);
  // self-attention
  gemm_bias_f16<<<dim3(6, 256), 256, 0, stream>>>(trg_h, wt_sa_qkv, bsa, qkv, 768);
  attn_mfma<<<2048, 256, 0, stream>>>(qkv, 768, qkv + 256, 768, qkv + 512, 768, attnb);
  lnproj_kernel<<<512, 256, 0, stream>>>(attnb, wt_sa_o, bsa + 768, trg, lng, lnb,
                                         hbuf, hh, nullptr);
  // cross-attention
  gemm_bias_f16<<<dim3(2, 256), 256, 0, stream>>>(hh, wt_ea_q, bea, qkv, 256);
  gemm_bias_f16<<<dim3(4, 256), 256, 0, stream>>>(src_h, wt_ea_kv, bea + 256, kvb, 512);
  attn_mfma<<<2048, 256, 0, stream>>>(qkv, 256, kvb, 512, kvb + 256, 512, attnb);
  lnproj_kernel<<<512, 256, 0, stream>>>(attnb, wt_ea_o, bea + 768, hbuf, lng, lnb,
                                         hbuf, nullptr, norms);
  // fused pooling + FC head
  head_kernel<<<64, 512, 0, stream>>>(norms, hbuf, Wfc1, bfc1, Wfc2, bfc2,
                                      Wout, bout, out);

  (void)in_sizes; (void)n_in; (void)out_size; (void)ws_size;
}

// Round 9
// 354.636 us; speedup vs baseline: 1.1004x; 1.1004x over previous
//
#include <hip/hip_runtime.h>

typedef unsigned short u16;
typedef __attribute__((ext_vector_type(8))) short s16x8;      // raw 16B staging
typedef __attribute__((ext_vector_type(8))) _Float16 f16x8;   // MFMA fragments
typedef __attribute__((ext_vector_type(4))) float f32x4;

#define ASYNC16(gp, lp) \
  __builtin_amdgcn_global_load_lds((__attribute__((address_space(1))) void*)(gp), \
                                   (__attribute__((address_space(3))) void*)(lp), 16, 0, 0)

__device__ __forceinline__ u16 f2h(float f) {
  _Float16 h = (_Float16)f;
  union { _Float16 h; u16 u; } v; v.h = h;
  return v.u;
}
__device__ __forceinline__ float h2f(u16 s) {
  union { _Float16 h; u16 u; } v; v.u = s; return (float)v.h;
}

__device__ __forceinline__ int swz4(int row) { return (row & 3) ^ ((row >> 2) & 3); }

// ---------------------------------------------------------------------------
// prep: cast trg/src fp32->fp16; transpose+cast weights into Wt[n][k] fp16.
// (verified round 4)
// ---------------------------------------------------------------------------
__global__ __launch_bounds__(256) void prep_kernel(
    const float* __restrict__ trg, const float* __restrict__ src,
    const float* __restrict__ Wsa, const float* __restrict__ Wea,
    u16* __restrict__ trg_h, u16* __restrict__ src_h, u16* __restrict__ wt)
{
  int blk = blockIdx.x, tid = threadIdx.x;
  if (blk < 8192) {
    const float* sp = (blk < 4096) ? trg : src;
    u16* dp = (blk < 4096) ? trg_h : src_h;
    size_t base = ((size_t)(blk & 4095) * 256 + tid) * 8;
    float4 a = *(const float4*)(sp + base);
    float4 c = *(const float4*)(sp + base + 4);
    s16x8 o;
    o[0] = (short)f2h(a.x); o[1] = (short)f2h(a.y);
    o[2] = (short)f2h(a.z); o[3] = (short)f2h(a.w);
    o[4] = (short)f2h(c.x); o[5] = (short)f2h(c.y);
    o[6] = (short)f2h(c.z); o[7] = (short)f2h(c.w);
    *(s16x8*)(dp + base) = o;
  } else {
    int t = (blk - 8192) * 256 + tid;       // < 524288
    int row = t >> 8, k = t & 255;
    const float* W; int sel, col;
    if (row < 768)       { W = Wsa; sel = row >> 8;              col = row & 255; }
    else if (row < 1024) { W = Wsa; sel = 3;                     col = row & 255; }
    else if (row < 1280) { W = Wea; sel = 0;                     col = row & 255; }
    else if (row < 1792) { W = Wea; sel = ((row - 1280) >> 8) + 1; col = (row - 1280) & 255; }
    else                 { W = Wea; sel = 3;                     col = row & 255; }
    wt[(size_t)row * 256 + k] = f2h(W[sel * 65536 + k * 256 + col]);
  }
}

// ---------------------------------------------------------------------------
// fp16 MFMA GEMM (verified round 4): C[M][N] = A[M][256] @ Bt[N][256]^T + bias.
// ---------------------------------------------------------------------------
__global__ __launch_bounds__(256, 3) void gemm_bias_f16(
    const u16* __restrict__ A, const u16* __restrict__ Bt,
    const float* __restrict__ bias, u16* __restrict__ C, int N)
{
  __shared__ u16 Asm[128 * 32];
  __shared__ u16 Bsm[128 * 32];
  const int tid = threadIdx.x;
  const int wv = tid >> 6, ln = tid & 63;
  const int quad = ln >> 4, l16 = ln & 15;
  const int nblk = blockIdx.x;
  const size_t arow0 = (size_t)blockIdx.y * 128;
  const size_t brow0 = (size_t)nblk * 128;
  const int wr = wv >> 1, wc = wv & 1;
  f32x4 acc[4][4];
  const f32x4 VZERO = {0.f, 0.f, 0.f, 0.f};
#pragma unroll
  for (int i = 0; i < 4; ++i)
#pragma unroll
    for (int j = 0; j < 4; ++j) acc[i][j] = VZERO;

  for (int k0 = 0; k0 < 256; k0 += 32) {
    __syncthreads();
#pragma unroll
    for (int j = 0; j < 2; ++j) {
      int c = (j * 4 + wv) * 64 + ln;
      int row = c >> 2, slot = c & 3;
      int kc = slot ^ swz4(row);
      ASYNC16(A + (arow0 + row) * 256 + k0 + kc * 8, Asm + c * 8);
      ASYNC16(Bt + (brow0 + row) * 256 + k0 + kc * 8, Bsm + c * 8);
    }
    __syncthreads();
    f16x8 af[4], bfr[4];
#pragma unroll
    for (int mt = 0; mt < 4; ++mt) {
      int tr = wr * 64 + mt * 16 + l16;
      int slot = quad ^ swz4(tr);
      af[mt] = *(const f16x8*)(Asm + (tr * 4 + slot) * 8);
    }
#pragma unroll
    for (int nt = 0; nt < 4; ++nt) {
      int tr = wc * 64 + nt * 16 + l16;
      int slot = quad ^ swz4(tr);
      bfr[nt] = *(const f16x8*)(Bsm + (tr * 4 + slot) * 8);
    }
#pragma unroll
    for (int mt = 0; mt < 4; ++mt)
#pragma unroll
      for (int nt = 0; nt < 4; ++nt)
        acc[mt][nt] = __builtin_amdgcn_mfma_f32_16x16x32_f16(af[mt], bfr[nt], acc[mt][nt], 0, 0, 0);
  }
#pragma unroll
  for (int nt = 0; nt < 4; ++nt) {
    int col = nblk * 128 + wc * 64 + nt * 16 + l16;
    float bz = bias[col];
#pragma unroll
    for (int mt = 0; mt < 4; ++mt) {
      size_t row0 = arow0 + wr * 64 + mt * 16 + quad * 4;
#pragma unroll
      for (int r = 0; r < 4; ++r)
        C[(row0 + r) * (size_t)N + col] = f2h(acc[mt][nt][r] + bz);
    }
  }
}

// ---------------------------------------------------------------------------
// MFMA attention, no-max softmax (verified r5-8).
// ---------------------------------------------------------------------------
__global__ __launch_bounds__(256, 3) void attn_mfma(
    const u16* __restrict__ Qp, int ldq,
    const u16* __restrict__ Kp, int ldk,
    const u16* __restrict__ Vp, int ldv,
    u16* __restrict__ Op)
{
  __shared__ u16 Ks[256 * 40];
  __shared__ u16 Vt[32 * 296];
  __shared__ __align__(16) unsigned Pw[4][32 * 20];
  const int tid = threadIdx.x;
  const int wv = tid >> 6, ln = tid & 63;
  const int quad = ln >> 4, l16 = ln & 15;
  const int lin = blockIdx.x;
  const int qb = (lin >> 3) & 3;
  const int g = ((lin >> 5) << 3) | (lin & 7);   // 0..511, partners share XCD
  const int h = g & 7;
  const size_t rb = (size_t)(g >> 3) * 512;
  const f32x4 VZERO = {0.f, 0.f, 0.f, 0.f};

  f16x8 qf[2];
  const _Float16 qs = (_Float16)0.25503492f;    // (1/sqrt(32)) * log2(e)
#pragma unroll
  for (int mq = 0; mq < 2; ++mq) {
    int qrow = qb * 128 + wv * 32 + mq * 16 + l16;
    qf[mq] = *(const f16x8*)(Qp + (rb + qrow) * (size_t)ldq + h * 32 + quad * 8);
#pragma unroll
    for (int j = 0; j < 8; ++j) qf[mq][j] *= qs;
  }
  f16x8 onesf;
#pragma unroll
  for (int j = 0; j < 8; ++j) onesf[j] = (_Float16)1.0f;

  f32x4 o[2][2], osum[2];
#pragma unroll
  for (int mq = 0; mq < 2; ++mq) { o[mq][0] = VZERO; o[mq][1] = VZERO; osum[mq] = VZERO; }

  for (int kb = 0; kb < 2; ++kb) {
    __syncthreads();
#pragma unroll
    for (int it = 0; it < 4; ++it) {
      {
        int c = it * 256 + tid;
        int row = c >> 2, part = c & 3;
        s16x8 kv = *(const s16x8*)(Kp + (rb + kb * 256 + row) * (size_t)ldk + h * 32 + part * 8);
        *(s16x8*)(Ks + row * 40 + part * 8) = kv;
      }
      {
        int row = tid, part = it;
        s16x8 vv = *(const s16x8*)(Vp + (rb + kb * 256 + row) * (size_t)ldv + h * 32 + part * 8);
        int kts = row >> 5, l = row & 31;
        int p = 2 * (l & 15) + (l >> 4);           // key permutation
#pragma unroll
        for (int j = 0; j < 8; ++j) Vt[(part * 8 + j) * 296 + kts * 32 + p] = (u16)vv[j];
      }
    }
    __syncthreads();
    for (int kt = 0; kt < 8; ++kt) {
      f16x8 kf0 = *(const f16x8*)(Ks + (kt * 32 + l16) * 40 + quad * 8);
      f16x8 kf1 = *(const f16x8*)(Ks + (kt * 32 + 16 + l16) * 40 + quad * 8);
      f16x8 vf0 = *(const f16x8*)(Vt + l16 * 296 + kt * 32 + quad * 8);
      f16x8 vf1 = *(const f16x8*)(Vt + (16 + l16) * 296 + kt * 32 + quad * 8);
#pragma unroll
      for (int mq = 0; mq < 2; ++mq) {
        f32x4 s0 = __builtin_amdgcn_mfma_f32_16x16x32_f16(qf[mq], kf0, VZERO, 0, 0, 0);
        f32x4 s1 = __builtin_amdgcn_mfma_f32_16x16x32_f16(qf[mq], kf1, VZERO, 0, 0, 0);
#pragma unroll
        for (int r = 0; r < 4; ++r) {
          float e0 = __builtin_amdgcn_exp2f(s0[r]);
          float e1 = __builtin_amdgcn_exp2f(s1[r]);
          union { _Float16 h2[2]; unsigned u; } pk;
          pk.h2[0] = (_Float16)e0; pk.h2[1] = (_Float16)e1;
          Pw[wv][(mq * 16 + quad * 4 + r) * 20 + l16] = pk.u;
        }
      }
#pragma unroll
      for (int mq = 0; mq < 2; ++mq) {
        f16x8 pf = *(const f16x8*)(&Pw[wv][(mq * 16 + l16) * 20 + quad * 4]);
        o[mq][0] = __builtin_amdgcn_mfma_f32_16x16x32_f16(pf, vf0, o[mq][0], 0, 0, 0);
        o[mq][1] = __builtin_amdgcn_mfma_f32_16x16x32_f16(pf, vf1, o[mq][1], 0, 0, 0);
        osum[mq] = __builtin_amdgcn_mfma_f32_16x16x32_f16(pf, onesf, osum[mq], 0, 0, 0);
      }
    }
  }
#pragma unroll
  for (int mq = 0; mq < 2; ++mq)
#pragma unroll
    for (int r = 0; r < 4; ++r) {
      float inv = 1.f / osum[mq][r];
      size_t row = rb + qb * 128 + wv * 32 + mq * 16 + quad * 4 + r;
      Op[row * 256 + h * 32 + l16]      = f2h(o[mq][0][r] * inv);
      Op[row * 256 + h * 32 + 16 + l16] = f2h(o[mq][1][r] * inv);
    }
}

// ---------------------------------------------------------------------------
// O-projection (MFMA) + bias + fp16 residual + LayerNorm -> fp16 h (+norms).
// Round 9: all-fp16 h pipeline (no fp32 h buffer).
// ---------------------------------------------------------------------------
__global__ __launch_bounds__(256, 3) void lnproj_kernel(
    const u16* __restrict__ A, const u16* __restrict__ Wt,
    const float* __restrict__ bo, const u16* __restrict__ resid,
    const float* __restrict__ g, const float* __restrict__ lb,
    u16* __restrict__ Hh, float* __restrict__ norms)
{
  __shared__ u16 Asm[64 * 32];
  __shared__ u16 Bsm[256 * 32];
  const int tid = threadIdx.x;
  const int wv = tid >> 6, ln = tid & 63;
  const int quad = ln >> 4, l16 = ln & 15;
  const size_t arow0 = (size_t)blockIdx.x * 64;
  f32x4 acc[16];
  const f32x4 VZERO = {0.f, 0.f, 0.f, 0.f};
#pragma unroll
  for (int nt = 0; nt < 16; ++nt) acc[nt] = VZERO;

  for (int k0 = 0; k0 < 256; k0 += 32) {
    __syncthreads();
    {
      int c = tid;
      int row = c >> 2, slot = c & 3;
      int kc = slot ^ swz4(row);
      ASYNC16(A + (arow0 + row) * 256 + k0 + kc * 8, Asm + c * 8);
    }
#pragma unroll
    for (int j = 0; j < 4; ++j) {
      int c = (j * 4 + wv) * 64 + ln;
      int row = c >> 2, slot = c & 3;
      int kc = slot ^ swz4(row);
      ASYNC16(Wt + (size_t)row * 256 + k0 + kc * 8, Bsm + c * 8);
    }
    __syncthreads();
    int tr = wv * 16 + l16;
    int aslot = quad ^ swz4(tr);
    f16x8 af = *(const f16x8*)(Asm + (tr * 4 + aslot) * 8);
#pragma unroll
    for (int nt = 0; nt < 16; ++nt) {
      int br = nt * 16 + l16;
      int bslot = quad ^ swz4(br);
      f16x8 bfr = *(const f16x8*)(Bsm + (br * 4 + bslot) * 8);
      acc[nt] = __builtin_amdgcn_mfma_f32_16x16x32_f16(af, bfr, acc[nt], 0, 0, 0);
    }
  }
  float gv[16], bv[16], bov[16];
#pragma unroll
  for (int nt = 0; nt < 16; ++nt) {
    int col = nt * 16 + l16;
    gv[nt] = g[col]; bv[nt] = lb[col]; bov[nt] = bo[col];
  }
#pragma unroll
  for (int r = 0; r < 4; ++r) {
    size_t row = arow0 + wv * 16 + quad * 4 + r;
    const u16* rrow = resid + row * 256;
    float vals[16]; float s = 0.f;
#pragma unroll
    for (int nt = 0; nt < 16; ++nt) {
      float v = acc[nt][r] + bov[nt] + h2f(rrow[nt * 16 + l16]);
      vals[nt] = v; s += v;
    }
#pragma unroll
    for (int m = 1; m < 16; m <<= 1) s += __shfl_xor(s, m);
    float mean = s * (1.f / 256.f);
    float sq = 0.f;
#pragma unroll
    for (int nt = 0; nt < 16; ++nt) { float d = vals[nt] - mean; sq = fmaf(d, d, sq); }
#pragma unroll
    for (int m = 1; m < 16; m <<= 1) sq += __shfl_xor(sq, m);
    float rstd = rsqrtf(sq * (1.f / 256.f) + 1e-5f);
    float ssq = 0.f;
#pragma unroll
    for (int nt = 0; nt < 16; ++nt) {
      float hv = (vals[nt] - mean) * rstd * gv[nt] + bv[nt];
      Hh[row * 256 + nt * 16 + l16] = f2h(hv);
      ssq = fmaf(hv, hv, ssq);
    }
    if (norms) {
#pragma unroll
      for (int m = 1; m < 16; m <<= 1) ssq += __shfl_xor(ssq, m);
      if (l16 == 0) norms[row] = sqrtf(ssq);
    }
  }
}

// ---------------------------------------------------------------------------
// Pooling softmax (verified) — normalizes w in-place, zeroes pooled.
// ---------------------------------------------------------------------------
__global__ __launch_bounds__(256) void softmax_kernel(const float* norms, float* w,
                                                      float* __restrict__ pooled)
{
  int b = blockIdx.x, tid = threadIdx.x;
  int ln = tid & 63, wvi = tid >> 6;
  __shared__ float red[8];
  const float* nb = norms + b * 512;
  float n0 = nb[tid], n1 = nb[tid + 256];
  float mx = fmaxf(n0, n1);
#pragma unroll
  for (int m = 1; m < 64; m <<= 1) mx = fmaxf(mx, __shfl_xor(mx, m));
  if (ln == 0) red[wvi] = mx;
  __syncthreads();
  mx = fmaxf(fmaxf(red[0], red[1]), fmaxf(red[2], red[3]));
  float e0 = __expf(n0 - mx), e1 = __expf(n1 - mx);
  float s = e0 + e1;
#pragma unroll
  for (int m = 1; m < 64; m <<= 1) s += __shfl_xor(s, m);
  if (ln == 0) red[4 + wvi] = s;
  __syncthreads();
  s = red[4] + red[5] + red[6] + red[7];
  float inv = 1.f / s;
  w[b * 512 + tid] = e0 * inv;
  w[b * 512 + tid + 256] = e1 * inv;
  pooled[b * 256 + tid] = 0.f;
}

__global__ __launch_bounds__(256) void poolsum_kernel(const float* __restrict__ w,
                                                      const u16* __restrict__ h,
                                                      float* __restrict__ pooled)
{
  int b = blockIdx.x, sl = blockIdx.y, d = threadIdx.x;
  const u16* hb = h + ((size_t)b * 512 + sl * 64) * 256 + d;
  const float* wb = w + b * 512 + sl * 64;
  float acc = 0.f;
#pragma unroll 8
  for (int a = 0; a < 64; ++a) acc = fmaf(wb[a], h2f(hb[(size_t)a * 256]), acc);
  atomicAdd(&pooled[b * 256 + d], acc);
}

// ---------------------------------------------------------------------------
// FC stack, parallelized (verified round 7): fc1 then fused fc2+out.
// ---------------------------------------------------------------------------
__global__ __launch_bounds__(512) void fc1_kernel(
    const float* __restrict__ pooled, const float* __restrict__ Wfc1,
    const float* __restrict__ bfc1, float* __restrict__ x1)
{
  int b = blockIdx.x, tid = threadIdx.x;
  __shared__ float px[256];
  if (tid < 256) px[tid] = pooled[b * 256 + tid];
  __syncthreads();
  float a = bfc1[tid];
#pragma unroll 8
  for (int d = 0; d < 256; ++d) a = fmaf(px[d], Wfc1[d * 512 + tid], a);
  x1[b * 512 + tid] = fmaxf(a, 0.f);
}

__global__ __launch_bounds__(512) void fc23_kernel(
    const float* __restrict__ x1, const float* __restrict__ Wfc2,
    const float* __restrict__ bfc2, const float* __restrict__ Wout,
    const float* __restrict__ bout, float* __restrict__ out)
{
  int b = blockIdx.x, tid = threadIdx.x;
  __shared__ float sx[512];
  __shared__ float rr[16];
  sx[tid] = x1[b * 512 + tid];
  __syncthreads();
  float a = bfc2[tid];
#pragma unroll 8
  for (int d = 0; d < 512; ++d) a = fmaf(sx[d], Wfc2[d * 512 + tid], a);
  a = fmaxf(a, 0.f);
  float p0 = a * Wout[tid * 2];
  float p1 = a * Wout[tid * 2 + 1];
  int ln = tid & 63, wvi = tid >> 6;
#pragma unroll
  for (int m = 1; m < 64; m <<= 1) { p0 += __shfl_xor(p0, m); p1 += __shfl_xor(p1, m); }
  if (ln == 0) { rr[wvi] = p0; rr[8 + wvi] = p1; }
  __syncthreads();
  if (tid == 0) {
    float s = 0.f;
#pragma unroll
    for (int i = 0; i < 8; ++i) s += rr[i];
    out[b * 2] = s + bout[0];
  }
  if (tid == 1) {
    float s = 0.f;
#pragma unroll
    for (int i = 0; i < 8; ++i) s += rr[8 + i];
    out[b * 2 + 1] = s + bout[1];
  }
}

// ---------------------------------------------------------------------------
extern "C" void kernel_launch(void* const* d_in, const int* in_sizes, int n_in,
                              void* d_out, int out_size, void* d_ws, size_t ws_size,
                              hipStream_t stream) {
  const float* trg  = (const float*)d_in[0];
  const float* src  = (const float*)d_in[1];
  const float* Wsa  = (const float*)d_in[2];
  const float* bsa  = (const float*)d_in[3];
  const float* Wea  = (const float*)d_in[4];
  const float* bea  = (const float*)d_in[5];
  const float* lng  = (const float*)d_in[6];
  const float* lnb  = (const float*)d_in[7];
  const float* Wfc1 = (const float*)d_in[8];
  const float* bfc1 = (const float*)d_in[9];
  const float* Wfc2 = (const float*)d_in[10];
  const float* bfc2 = (const float*)d_in[11];
  const float* Wout = (const float*)d_in[12];
  const float* bout = (const float*)d_in[13];
  float* out = (float*)d_out;

  const size_t M = 32768;  // B*A
  char* ws = (char*)d_ws;
  u16* trg_h = (u16*)ws;                ws += M * 256 * 2;
  u16* src_h = (u16*)ws;                ws += M * 256 * 2;
  u16* wt     = (u16*)ws;               ws += 2048 * 256 * 2;
  u16* qkv    = (u16*)ws;               ws += M * 768 * 2;
  u16* attnb  = (u16*)ws;               ws += M * 256 * 2;
  u16* hh     = (u16*)ws;               ws += M * 256 * 2;
  u16* h2h    = (u16*)ws;               ws += M * 256 * 2;
  float* norms = (float*)ws;            ws += M * 4;
  float* pooled = (float*)ws;           ws += 64 * 256 * 4;
  float* x1buf = (float*)ws;            ws += 64 * 512 * 4;

  u16* wt_sa_qkv = wt;
  u16* wt_sa_o   = wt + 768 * 256;
  u16* wt_ea_q   = wt + 1024 * 256;
  u16* wt_ea_kv  = wt + 1280 * 256;
  u16* wt_ea_o   = wt + 1792 * 256;
  u16* kvb = qkv + M * 256;

  prep_kernel<<<10240, 256, 0, stream>>>(trg, src, Wsa, Wea, trg_h, src_h, wt);
  // self-attention
  gemm_bias_f16<<<dim3(6, 256), 256, 0, stream>>>(trg_h, wt_sa_qkv, bsa, qkv, 768);
  attn_mfma<<<2048, 256, 0, stream>>>(qkv, 768, qkv + 256, 768, qkv + 512, 768, attnb);
  lnproj_kernel<<<512, 256, 0, stream>>>(attnb, wt_sa_o, bsa + 768, trg_h, lng, lnb,
                                         hh, nullptr);
  // cross-attention
  gemm_bias_f16<<<dim3(2, 256), 256, 0, stream>>>(hh, wt_ea_q, bea, qkv, 256);
  gemm_bias_f16<<<dim3(4, 256), 256, 0, stream>>>(src_h, wt_ea_kv, bea + 256, kvb, 512);
  attn_mfma<<<2048, 256, 0, stream>>>(qkv, 256, kvb, 512, kvb + 256, 512, attnb);
  lnproj_kernel<<<512, 256, 0, stream>>>(attnb, wt_ea_o, bea + 768, hh, lng, lnb,
                                         h2h, norms);
  // pooling + FC head
  softmax_kernel<<<64, 256, 0, stream>>>(norms, norms, pooled);
  poolsum_kernel<<<dim3(64, 8), 256, 0, stream>>>(norms, h2h, pooled);
  fc1_kernel<<<64, 512, 0, stream>>>(pooled, Wfc1, bfc1, x1buf);
  fc23_kernel<<<64, 512, 0, stream>>>(x1buf, Wfc2, bfc2, Wout, bout, out);

  (void)in_sizes; (void)n_in; (void)out_size; (void)ws_size;
}

// Round 10
// 339.099 us; speedup vs baseline: 1.1508x; 1.0458x over previous
//
#include <hip/hip_runtime.h>

typedef unsigned short u16;
typedef __attribute__((ext_vector_type(8))) short s16x8;      // raw 16B staging
typedef __attribute__((ext_vector_type(8))) _Float16 f16x8;   // MFMA fragments
typedef __attribute__((ext_vector_type(4))) float f32x4;

#define ASYNC16(gp, lp) \
  __builtin_amdgcn_global_load_lds((__attribute__((address_space(1))) void*)(gp), \
                                   (__attribute__((address_space(3))) void*)(lp), 16, 0, 0)

__device__ __forceinline__ u16 f2h(float f) {
  _Float16 h = (_Float16)f;
  union { _Float16 h; u16 u; } v; v.h = h;
  return v.u;
}
__device__ __forceinline__ float h2f(u16 s) {
  union { _Float16 h; u16 u; } v; v.u = s; return (float)v.h;
}

__device__ __forceinline__ int swz4(int row) { return (row & 3) ^ ((row >> 2) & 3); }

// ---------------------------------------------------------------------------
// prep: cast trg/src fp32->fp16; transpose+cast weights into Wt[n][k] fp16.
// (verified round 4)
// ---------------------------------------------------------------------------
__global__ __launch_bounds__(256) void prep_kernel(
    const float* __restrict__ trg, const float* __restrict__ src,
    const float* __restrict__ Wsa, const float* __restrict__ Wea,
    u16* __restrict__ trg_h, u16* __restrict__ src_h, u16* __restrict__ wt)
{
  int blk = blockIdx.x, tid = threadIdx.x;
  if (blk < 8192) {
    const float* sp = (blk < 4096) ? trg : src;
    u16* dp = (blk < 4096) ? trg_h : src_h;
    size_t base = ((size_t)(blk & 4095) * 256 + tid) * 8;
    float4 a = *(const float4*)(sp + base);
    float4 c = *(const float4*)(sp + base + 4);
    s16x8 o;
    o[0] = (short)f2h(a.x); o[1] = (short)f2h(a.y);
    o[2] = (short)f2h(a.z); o[3] = (short)f2h(a.w);
    o[4] = (short)f2h(c.x); o[5] = (short)f2h(c.y);
    o[6] = (short)f2h(c.z); o[7] = (short)f2h(c.w);
    *(s16x8*)(dp + base) = o;
  } else {
    int t = (blk - 8192) * 256 + tid;       // < 524288
    int row = t >> 8, k = t & 255;
    const float* W; int sel, col;
    if (row < 768)       { W = Wsa; sel = row >> 8;              col = row & 255; }
    else if (row < 1024) { W = Wsa; sel = 3;                     col = row & 255; }
    else if (row < 1280) { W = Wea; sel = 0;                     col = row & 255; }
    else if (row < 1792) { W = Wea; sel = ((row - 1280) >> 8) + 1; col = (row - 1280) & 255; }
    else                 { W = Wea; sel = 3;                     col = row & 255; }
    wt[(size_t)row * 256 + k] = f2h(W[sel * 65536 + k * 256 + col]);
  }
}

// ---------------------------------------------------------------------------
// fp16 MFMA GEMM (verified round 4): C[M][N] = A[M][256] @ Bt[N][256]^T + bias.
// ---------------------------------------------------------------------------
__global__ __launch_bounds__(256, 3) void gemm_bias_f16(
    const u16* __restrict__ A, const u16* __restrict__ Bt,
    const float* __restrict__ bias, u16* __restrict__ C, int N)
{
  __shared__ u16 Asm[128 * 32];
  __shared__ u16 Bsm[128 * 32];
  const int tid = threadIdx.x;
  const int wv = tid >> 6, ln = tid & 63;
  const int quad = ln >> 4, l16 = ln & 15;
  const int nblk = blockIdx.x;
  const size_t arow0 = (size_t)blockIdx.y * 128;
  const size_t brow0 = (size_t)nblk * 128;
  const int wr = wv >> 1, wc = wv & 1;
  f32x4 acc[4][4];
  const f32x4 VZERO = {0.f, 0.f, 0.f, 0.f};
#pragma unroll
  for (int i = 0; i < 4; ++i)
#pragma unroll
    for (int j = 0; j < 4; ++j) acc[i][j] = VZERO;

  for (int k0 = 0; k0 < 256; k0 += 32) {
    __syncthreads();
#pragma unroll
    for (int j = 0; j < 2; ++j) {
      int c = (j * 4 + wv) * 64 + ln;
      int row = c >> 2, slot = c & 3;
      int kc = slot ^ swz4(row);
      ASYNC16(A + (arow0 + row) * 256 + k0 + kc * 8, Asm + c * 8);
      ASYNC16(Bt + (brow0 + row) * 256 + k0 + kc * 8, Bsm + c * 8);
    }
    __syncthreads();
    f16x8 af[4], bfr[4];
#pragma unroll
    for (int mt = 0; mt < 4; ++mt) {
      int tr = wr * 64 + mt * 16 + l16;
      int slot = quad ^ swz4(tr);
      af[mt] = *(const f16x8*)(Asm + (tr * 4 + slot) * 8);
    }
#pragma unroll
    for (int nt = 0; nt < 4; ++nt) {
      int tr = wc * 64 + nt * 16 + l16;
      int slot = quad ^ swz4(tr);
      bfr[nt] = *(const f16x8*)(Bsm + (tr * 4 + slot) * 8);
    }
#pragma unroll
    for (int mt = 0; mt < 4; ++mt)
#pragma unroll
      for (int nt = 0; nt < 4; ++nt)
        acc[mt][nt] = __builtin_amdgcn_mfma_f32_16x16x32_f16(af[mt], bfr[nt], acc[mt][nt], 0, 0, 0);
  }
#pragma unroll
  for (int nt = 0; nt < 4; ++nt) {
    int col = nblk * 128 + wc * 64 + nt * 16 + l16;
    float bz = bias[col];
#pragma unroll
    for (int mt = 0; mt < 4; ++mt) {
      size_t row0 = arow0 + wr * 64 + mt * 16 + quad * 4;
#pragma unroll
      for (int r = 0; r < 4; ++r)
        C[(row0 + r) * (size_t)N + col] = f2h(acc[mt][nt][r] + bz);
    }
  }
}

// ---------------------------------------------------------------------------
// MFMA attention, no-max softmax — EXACT round-7 version (measured 42.7 us).
// r8/r9's V-staging remap reverted: it halved LDS conflicts but quadrupled
// L1 transactions on the global V read (16B/lane scattered vs 64B-line
// consumed per instr) — net +10 us. Keep r7 geometry.
// ---------------------------------------------------------------------------
__global__ __launch_bounds__(256, 3) void attn_mfma(
    const u16* __restrict__ Qp, int ldq,
    const u16* __restrict__ Kp, int ldk,
    const u16* __restrict__ Vp, int ldv,
    u16* __restrict__ Op)
{
  __shared__ u16 Ks[256 * 40];
  __shared__ u16 Vt[32 * 264];
  __shared__ __align__(16) unsigned Pw[4][32 * 20];
  const int tid = threadIdx.x;
  const int wv = tid >> 6, ln = tid & 63;
  const int quad = ln >> 4, l16 = ln & 15;
  const int lin = blockIdx.x;
  const int qb = (lin >> 3) & 3;
  const int g = ((lin >> 5) << 3) | (lin & 7);   // 0..511, partners share XCD
  const int h = g & 7;
  const size_t rb = (size_t)(g >> 3) * 512;
  const f32x4 VZERO = {0.f, 0.f, 0.f, 0.f};

  f16x8 qf[2];
  const _Float16 qs = (_Float16)0.25503492f;    // (1/sqrt(32)) * log2(e)
#pragma unroll
  for (int mq = 0; mq < 2; ++mq) {
    int qrow = qb * 128 + wv * 32 + mq * 16 + l16;
    qf[mq] = *(const f16x8*)(Qp + (rb + qrow) * (size_t)ldq + h * 32 + quad * 8);
#pragma unroll
    for (int j = 0; j < 8; ++j) qf[mq][j] *= qs;
  }
  f16x8 onesf;
#pragma unroll
  for (int j = 0; j < 8; ++j) onesf[j] = (_Float16)1.0f;

  f32x4 o[2][2], osum[2];
#pragma unroll
  for (int mq = 0; mq < 2; ++mq) { o[mq][0] = VZERO; o[mq][1] = VZERO; osum[mq] = VZERO; }

  for (int kb = 0; kb < 2; ++kb) {
    __syncthreads();
    for (int c = tid; c < 1024; c += 256) {
      int row = c >> 2, part = c & 3;
      s16x8 kv = *(const s16x8*)(Kp + (rb + kb * 256 + row) * (size_t)ldk + h * 32 + part * 8);
      *(s16x8*)(Ks + row * 40 + part * 8) = kv;
      s16x8 vv = *(const s16x8*)(Vp + (rb + kb * 256 + row) * (size_t)ldv + h * 32 + part * 8);
      int kts = row >> 5, l = row & 31;
      int p = 2 * (l & 15) + (l >> 4);           // key permutation
#pragma unroll
      for (int j = 0; j < 8; ++j) Vt[(part * 8 + j) * 264 + kts * 32 + p] = (u16)vv[j];
    }
    __syncthreads();
    for (int kt = 0; kt < 8; ++kt) {
      f16x8 kf0 = *(const f16x8*)(Ks + (kt * 32 + l16) * 40 + quad * 8);
      f16x8 kf1 = *(const f16x8*)(Ks + (kt * 32 + 16 + l16) * 40 + quad * 8);
      f16x8 vf0 = *(const f16x8*)(Vt + l16 * 264 + kt * 32 + quad * 8);
      f16x8 vf1 = *(const f16x8*)(Vt + (16 + l16) * 264 + kt * 32 + quad * 8);
#pragma unroll
      for (int mq = 0; mq < 2; ++mq) {
        f32x4 s0 = __builtin_amdgcn_mfma_f32_16x16x32_f16(qf[mq], kf0, VZERO, 0, 0, 0);
        f32x4 s1 = __builtin_amdgcn_mfma_f32_16x16x32_f16(qf[mq], kf1, VZERO, 0, 0, 0);
#pragma unroll
        for (int r = 0; r < 4; ++r) {
          float e0 = __builtin_amdgcn_exp2f(s0[r]);
          float e1 = __builtin_amdgcn_exp2f(s1[r]);
          union { _Float16 h2[2]; unsigned u; } pk;
          pk.h2[0] = (_Float16)e0; pk.h2[1] = (_Float16)e1;
          Pw[wv][(mq * 16 + quad * 4 + r) * 20 + l16] = pk.u;
        }
      }
#pragma unroll
      for (int mq = 0; mq < 2; ++mq) {
        f16x8 pf = *(const f16x8*)(&Pw[wv][(mq * 16 + l16) * 20 + quad * 4]);
        o[mq][0] = __builtin_amdgcn_mfma_f32_16x16x32_f16(pf, vf0, o[mq][0], 0, 0, 0);
        o[mq][1] = __builtin_amdgcn_mfma_f32_16x16x32_f16(pf, vf1, o[mq][1], 0, 0, 0);
        osum[mq] = __builtin_amdgcn_mfma_f32_16x16x32_f16(pf, onesf, osum[mq], 0, 0, 0);
      }
    }
  }
#pragma unroll
  for (int mq = 0; mq < 2; ++mq)
#pragma unroll
    for (int r = 0; r < 4; ++r) {
      float inv = 1.f / osum[mq][r];
      size_t row = rb + qb * 128 + wv * 32 + mq * 16 + quad * 4 + r;
      Op[row * 256 + h * 32 + l16]      = f2h(o[mq][0][r] * inv);
      Op[row * 256 + h * 32 + 16 + l16] = f2h(o[mq][1][r] * inv);
    }
}

// ---------------------------------------------------------------------------
// O-projection (MFMA) + bias + fp16 residual + LayerNorm -> fp16 h (+norms).
// (verified round 9)
// ---------------------------------------------------------------------------
__global__ __launch_bounds__(256, 3) void lnproj_kernel(
    const u16* __restrict__ A, const u16* __restrict__ Wt,
    const float* __restrict__ bo, const u16* __restrict__ resid,
    const float* __restrict__ g, const float* __restrict__ lb,
    u16* __restrict__ Hh, float* __restrict__ norms)
{
  __shared__ u16 Asm[64 * 32];
  __shared__ u16 Bsm[256 * 32];
  const int tid = threadIdx.x;
  const int wv = tid >> 6, ln = tid & 63;
  const int quad = ln >> 4, l16 = ln & 15;
  const size_t arow0 = (size_t)blockIdx.x * 64;
  f32x4 acc[16];
  const f32x4 VZERO = {0.f, 0.f, 0.f, 0.f};
#pragma unroll
  for (int nt = 0; nt < 16; ++nt) acc[nt] = VZERO;

  for (int k0 = 0; k0 < 256; k0 += 32) {
    __syncthreads();
    {
      int c = tid;
      int row = c >> 2, slot = c & 3;
      int kc = slot ^ swz4(row);
      ASYNC16(A + (arow0 + row) * 256 + k0 + kc * 8, Asm + c * 8);
    }
#pragma unroll
    for (int j = 0; j < 4; ++j) {
      int c = (j * 4 + wv) * 64 + ln;
      int row = c >> 2, slot = c & 3;
      int kc = slot ^ swz4(row);
      ASYNC16(Wt + (size_t)row * 256 + k0 + kc * 8, Bsm + c * 8);
    }
    __syncthreads();
    int tr = wv * 16 + l16;
    int aslot = quad ^ swz4(tr);
    f16x8 af = *(const f16x8*)(Asm + (tr * 4 + aslot) * 8);
#pragma unroll
    for (int nt = 0; nt < 16; ++nt) {
      int br = nt * 16 + l16;
      int bslot = quad ^ swz4(br);
      f16x8 bfr = *(const f16x8*)(Bsm + (br * 4 + bslot) * 8);
      acc[nt] = __builtin_amdgcn_mfma_f32_16x16x32_f16(af, bfr, acc[nt], 0, 0, 0);
    }
  }
  float gv[16], bv[16], bov[16];
#pragma unroll
  for (int nt = 0; nt < 16; ++nt) {
    int col = nt * 16 + l16;
    gv[nt] = g[col]; bv[nt] = lb[col]; bov[nt] = bo[col];
  }
#pragma unroll
  for (int r = 0; r < 4; ++r) {
    size_t row = arow0 + wv * 16 + quad * 4 + r;
    const u16* rrow = resid + row * 256;
    float vals[16]; float s = 0.f;
#pragma unroll
    for (int nt = 0; nt < 16; ++nt) {
      float v = acc[nt][r] + bov[nt] + h2f(rrow[nt * 16 + l16]);
      vals[nt] = v; s += v;
    }
#pragma unroll
    for (int m = 1; m < 16; m <<= 1) s += __shfl_xor(s, m);
    float mean = s * (1.f / 256.f);
    float sq = 0.f;
#pragma unroll
    for (int nt = 0; nt < 16; ++nt) { float d = vals[nt] - mean; sq = fmaf(d, d, sq); }
#pragma unroll
    for (int m = 1; m < 16; m <<= 1) sq += __shfl_xor(sq, m);
    float rstd = rsqrtf(sq * (1.f / 256.f) + 1e-5f);
    float ssq = 0.f;
#pragma unroll
    for (int nt = 0; nt < 16; ++nt) {
      float hv = (vals[nt] - mean) * rstd * gv[nt] + bv[nt];
      Hh[row * 256 + nt * 16 + l16] = f2h(hv);
      ssq = fmaf(hv, hv, ssq);
    }
    if (norms) {
#pragma unroll
      for (int m = 1; m < 16; m <<= 1) ssq += __shfl_xor(ssq, m);
      if (l16 == 0) norms[row] = sqrtf(ssq);
    }
  }
}

// ---------------------------------------------------------------------------
// Pooling softmax (verified) — normalizes w in-place, zeroes pooled.
// ---------------------------------------------------------------------------
__global__ __launch_bounds__(256) void softmax_kernel(const float* norms, float* w,
                                                      float* __restrict__ pooled)
{
  int b = blockIdx.x, tid = threadIdx.x;
  int ln = tid & 63, wvi = tid >> 6;
  __shared__ float red[8];
  const float* nb = norms + b * 512;
  float n0 = nb[tid], n1 = nb[tid + 256];
  float mx = fmaxf(n0, n1);
#pragma unroll
  for (int m = 1; m < 64; m <<= 1) mx = fmaxf(mx, __shfl_xor(mx, m));
  if (ln == 0) red[wvi] = mx;
  __syncthreads();
  mx = fmaxf(fmaxf(red[0], red[1]), fmaxf(red[2], red[3]));
  float e0 = __expf(n0 - mx), e1 = __expf(n1 - mx);
  float s = e0 + e1;
#pragma unroll
  for (int m = 1; m < 64; m <<= 1) s += __shfl_xor(s, m);
  if (ln == 0) red[4 + wvi] = s;
  __syncthreads();
  s = red[4] + red[5] + red[6] + red[7];
  float inv = 1.f / s;
  w[b * 512 + tid] = e0 * inv;
  w[b * 512 + tid + 256] = e1 * inv;
  pooled[b * 256 + tid] = 0.f;
}

__global__ __launch_bounds__(256) void poolsum_kernel(const float* __restrict__ w,
                                                      const u16* __restrict__ h,
                                                      float* __restrict__ pooled)
{
  int b = blockIdx.x, sl = blockIdx.y, d = threadIdx.x;
  const u16* hb = h + ((size_t)b * 512 + sl * 64) * 256 + d;
  const float* wb = w + b * 512 + sl * 64;
  float acc = 0.f;
#pragma unroll 8
  for (int a = 0; a < 64; ++a) acc = fmaf(wb[a], h2f(hb[(size_t)a * 256]), acc);
  atomicAdd(&pooled[b * 256 + d], acc);
}

// ---------------------------------------------------------------------------
// FC stack, parallelized (verified round 7): fc1 then fused fc2+out.
// ---------------------------------------------------------------------------
__global__ __launch_bounds__(512) void fc1_kernel(
    const float* __restrict__ pooled, const float* __restrict__ Wfc1,
    const float* __restrict__ bfc1, float* __restrict__ x1)
{
  int b = blockIdx.x, tid = threadIdx.x;
  __shared__ float px[256];
  if (tid < 256) px[tid] = pooled[b * 256 + tid];
  __syncthreads();
  float a = bfc1[tid];
#pragma unroll 8
  for (int d = 0; d < 256; ++d) a = fmaf(px[d], Wfc1[d * 512 + tid], a);
  x1[b * 512 + tid] = fmaxf(a, 0.f);
}

__global__ __launch_bounds__(512) void fc23_kernel(
    const float* __restrict__ x1, const float* __restrict__ Wfc2,
    const float* __restrict__ bfc2, const float* __restrict__ Wout,
    const float* __restrict__ bout, float* __restrict__ out)
{
  int b = blockIdx.x, tid = threadIdx.x;
  __shared__ float sx[512];
  __shared__ float rr[16];
  sx[tid] = x1[b * 512 + tid];
  __syncthreads();
  float a = bfc2[tid];
#pragma unroll 8
  for (int d = 0; d < 512; ++d) a = fmaf(sx[d], Wfc2[d * 512 + tid], a);
  a = fmaxf(a, 0.f);
  float p0 = a * Wout[tid * 2];
  float p1 = a * Wout[tid * 2 + 1];
  int ln = tid & 63, wvi = tid >> 6;
#pragma unroll
  for (int m = 1; m < 64; m <<= 1) { p0 += __shfl_xor(p0, m); p1 += __shfl_xor(p1, m); }
  if (ln == 0) { rr[wvi] = p0; rr[8 + wvi] = p1; }
  __syncthreads();
  if (tid == 0) {
    float s = 0.f;
#pragma unroll
    for (int i = 0; i < 8; ++i) s += rr[i];
    out[b * 2] = s + bout[0];
  }
  if (tid == 1) {
    float s = 0.f;
#pragma unroll
    for (int i = 0; i < 8; ++i) s += rr[8 + i];
    out[b * 2 + 1] = s + bout[1];
  }
}

// ---------------------------------------------------------------------------
extern "C" void kernel_launch(void* const* d_in, const int* in_sizes, int n_in,
                              void* d_out, int out_size, void* d_ws, size_t ws_size,
                              hipStream_t stream) {
  const float* trg  = (const float*)d_in[0];
  const float* src  = (const float*)d_in[1];
  const float* Wsa  = (const float*)d_in[2];
  const float* bsa  = (const float*)d_in[3];
  const float* Wea  = (const float*)d_in[4];
  const float* bea  = (const float*)d_in[5];
  const float* lng  = (const float*)d_in[6];
  const float* lnb  = (const float*)d_in[7];
  const float* Wfc1 = (const float*)d_in[8];
  const float* bfc1 = (const float*)d_in[9];
  const float* Wfc2 = (const float*)d_in[10];
  const float* bfc2 = (const float*)d_in[11];
  const float* Wout = (const float*)d_in[12];
  const float* bout = (const float*)d_in[13];
  float* out = (float*)d_out;

  const size_t M = 32768;  // B*A
  char* ws = (char*)d_ws;
  u16* trg_h = (u16*)ws;                ws += M * 256 * 2;
  u16* src_h = (u16*)ws;                ws += M * 256 * 2;
  u16* wt     = (u16*)ws;               ws += 2048 * 256 * 2;
  u16* qkv    = (u16*)ws;               ws += M * 768 * 2;
  u16* attnb  = (u16*)ws;               ws += M * 256 * 2;
  u16* hh     = (u16*)ws;               ws += M * 256 * 2;
  u16* h2h    = (u16*)ws;               ws += M * 256 * 2;
  float* norms = (float*)ws;            ws += M * 4;
  float* pooled = (float*)ws;           ws += 64 * 256 * 4;
  float* x1buf = (float*)ws;            ws += 64 * 512 * 4;

  u16* wt_sa_qkv = wt;
  u16* wt_sa_o   = wt + 768 * 256;
  u16* wt_ea_q   = wt + 1024 * 256;
  u16* wt_ea_kv  = wt + 1280 * 256;
  u16* wt_ea_o   = wt + 1792 * 256;
  u16* kvb = qkv + M * 256;

  prep_kernel<<<10240, 256, 0, stream>>>(trg, src, Wsa, Wea, trg_h, src_h, wt);
  // self-attention
  gemm_bias_f16<<<dim3(6, 256), 256, 0, stream>>>(trg_h, wt_sa_qkv, bsa, qkv, 768);
  attn_mfma<<<2048, 256, 0, stream>>>(qkv, 768, qkv + 256, 768, qkv + 512, 768, attnb);
  lnproj_kernel<<<512, 256, 0, stream>>>(attnb, wt_sa_o, bsa + 768, trg_h, lng, lnb,
                                         hh, nullptr);
  // cross-attention
  gemm_bias_f16<<<dim3(2, 256), 256, 0, stream>>>(hh, wt_ea_q, bea, qkv, 256);
  gemm_bias_f16<<<dim3(4, 256), 256, 0, stream>>>(src_h, wt_ea_kv, bea + 256, kvb, 512);
  attn_mfma<<<2048, 256, 0, stream>>>(qkv, 256, kvb, 512, kvb + 256, 512, attnb);
  lnproj_kernel<<<512, 256, 0, stream>>>(attnb, wt_ea_o, bea + 768, hh, lng, lnb,
                                         h2h, norms);
  // pooling + FC head
  softmax_kernel<<<64, 256, 0, stream>>>(norms, norms, pooled);
  poolsum_kernel<<<dim3(64, 8), 256, 0, stream>>>(norms, h2h, pooled);
  fc1_kernel<<<64, 512, 0, stream>>>(pooled, Wfc1, bfc1, x1buf);
  fc23_kernel<<<64, 512, 0, stream>>>(x1buf, Wfc2, bfc2, Wout, bout, out);

  (void)in_sizes; (void)n_in; (void)out_size; (void)ws_size;
}